// Round 2
// 119.596 us; speedup vs baseline: 1.0263x; 1.0263x over previous
//
#include <hip/hip_runtime.h>
#include <math.h>

// MultiheadSelfAttention2D: C=256, AC=64, HEADS=16, HEAD_DIM=4, L=4096.
// R14 (resubmit; previous run failed on container acquisition, not code):
// Chebyshev-economized degree-4 attention basis (was Taylor T5).
// exp(x) on [-1,1] ~= sum_n g_n x^n, n<=4, max err 5.9e-4 (BETTER than
// T5's 1.6e-3) with only C(8,4)=70 monomials vs 126 (-44% monomial work
// in ssum/zvz/mmat/outfuse). Coefficient c_f = h_n/(a!b!c!d!) with
// h_n = n!*g_n from the Chebyshev series of exp (I_n(1) Bessel coeffs).
//   S_f = c_f sum_m k_m^a ;  Z_j = sum_f q_j^a S_f
//   M[f][d] = c_f sum_j q_j^a V[d,j]/Z_j ;  out[d,i] = sum_f k_i^a M[f][d]
// Structure otherwise = R10 (best measured): 5 dispatches, no atomics.
// Feature dim padded 70->72; pad slots carry workspace poison but are
// never consumed (guards in ssum/mmat writes, 70-iter consume loops).

constexpr int SL = 4096;
constexpr int NF = 70;      // C(4+4,4) monomials of degree <= 4
constexpr int FP = 72;      // padded feature stride

__device__ __forceinline__ float invfact(int e) {
    return e < 2 ? 1.f : e == 2 ? 0.5f : e == 3 ? (1.f / 6.f) : (1.f / 24.f);
}
// h_n = n! * g_n, g_n = monomial coeffs of the Chebyshev-economized
// degree-4 approx of exp on [-1,1]:
//   g0=1.00004478 g1=0.99730766 g2=0.49919676 g3=0.17734740 g4=0.04379392
__device__ __forceinline__ float hdeg(int n) {
    return n == 0 ? 1.00004478f : n == 1 ? 0.99730766f
         : n == 2 ? 0.99839351f : n == 3 ? 1.06408440f : 1.05105416f;
}
__device__ __forceinline__ void f2abcd(int f, int& A, int& B, int& C, int& D) {
    for (int a = 0; a <= 4; ++a)
        for (int b = 0; b <= 4 - a; ++b)
            for (int c = 0; c <= 4 - a - b; ++c)
                for (int d = 0; d <= 4 - a - b - c; ++d)
                    if (f-- == 0) { A = a; B = b; C = c; D = d; return; }
}

#define FOR_MONOMIALS(BODY)                         \
    {                                               \
        int f = 0;                                  \
        _Pragma("unroll")                           \
        for (int a = 0; a <= 4; ++a)                \
        _Pragma("unroll")                           \
        for (int b = 0; b <= 4 - a; ++b)            \
        _Pragma("unroll")                           \
        for (int c = 0; c <= 4 - a - b; ++c)        \
        _Pragma("unroll")                           \
        for (int d = 0; d <= 4 - a - b - c; ++d) {  \
            BODY;                                   \
            ++f;                                    \
        }                                           \
    }

#define BUILD_POWERS(q)                                   \
    float p0[5], p1[5], p2[5], p3[5];                     \
    p0[0] = p1[0] = p2[0] = p3[0] = 1.f;                  \
    _Pragma("unroll")                                     \
    for (int t_ = 1; t_ < 5; ++t_) {                      \
        p0[t_] = p0[t_ - 1] * (q).x; p1[t_] = p1[t_ - 1] * (q).y; \
        p2[t_] = p2[t_ - 1] * (q).z; p3[t_] = p3[t_ - 1] * (q).w; }

// ---------------------------------------------------------------------------
// Kernel 1: QKV projection + L2-norm. Grid (64 l-tiles, 12 row-blocks),
// block 256 (4 waves x 4 rows). No LDS: X streamed via L1/L2.
// ---------------------------------------------------------------------------
__global__ __launch_bounds__(256) void qkv_kernel(
    const float* __restrict__ X,
    const float* __restrict__ Wq, const float* __restrict__ bq,
    const float* __restrict__ Wk, const float* __restrict__ bk,
    const float* __restrict__ Wv, const float* __restrict__ bv,
    float* __restrict__ Qn, float* __restrict__ Kn, float* __restrict__ V4)
{
    const int tid  = threadIdx.x;
    const int lane = tid & 63;
    const int wv   = __builtin_amdgcn_readfirstlane(tid >> 6);
    const int lt   = blockIdx.x;
    const int rb   = blockIdx.y;               // 12 blocks of 16 rows
    const int type = rb >> 2;                  // 0=Q 1=K 2=V, block-uniform
    const int rit  = (rb & 3) * 16 + wv * 4;   // row-in-type, wave-uniform
    const int l    = lt * 64 + lane;

    const float* W = type == 0 ? Wq : type == 1 ? Wk : Wv;
    const float* B = type == 0 ? bq : type == 1 ? bk : bv;
    const float* w0 = W + (rit + 0) * 256;
    const float* w1 = W + (rit + 1) * 256;
    const float* w2 = W + (rit + 2) * 256;
    const float* w3 = W + (rit + 3) * 256;

    float y0 = B[rit + 0], y1 = B[rit + 1], y2 = B[rit + 2], y3 = B[rit + 3];
    const float* Xl = X + l;
    #pragma unroll 8
    for (int c = 0; c < 256; ++c) {
        float x = Xl[c * SL];
        y0 = fmaf(w0[c], x, y0);
        y1 = fmaf(w1[c], x, y1);
        y2 = fmaf(w2[c], x, y2);
        y3 = fmaf(w3[c], x, y3);
    }
    if (type < 2) {
        float n = sqrtf(y0*y0 + y1*y1 + y2*y2 + y3*y3);
        float inv = 1.f / fmaxf(n, 1e-12f);
        y0 *= inv; y1 *= inv; y2 *= inv; y3 *= inv;
    }
    const int h = rit >> 2;
    float* base = type == 0 ? Qn : type == 1 ? Kn : V4;
    ((float4*)base)[h * SL + l] = make_float4(y0, y1, y2, y3);
}

// ---------------------------------------------------------------------------
// Kernel 2: Sp[jc][h][f] = c_f * sum over j-chunk(1024) of k^a.
// Grid (9 f-chunks, 16 h, 4 jc) = 576 blocks (2.25/CU).
// ---------------------------------------------------------------------------
template <int FC>
__device__ __forceinline__ void psi_accum(int h, int jc, int tid,
        const float* __restrict__ Kn, float acc[8])
{
    for (int u = 0; u < 4; ++u) {
        int j = jc * 1024 + u * 256 + tid;
        float4 k = ((const float4*)Kn)[h * SL + j];
        BUILD_POWERS(k)
        FOR_MONOMIALS({
            if (f >= FC * 8 && f < FC * 8 + 8)
                acc[f - FC * 8] += (p0[a] * p1[b]) * (p2[c] * p3[d]);
        })
    }
}

__global__ __launch_bounds__(256) void ssum_kernel(
    const float* __restrict__ Kn, float* __restrict__ Sp)
{
    const int tid = threadIdx.x;
    const int fc  = blockIdx.x;
    const int h   = blockIdx.y;
    const int jc  = blockIdx.z;
    float acc[8];
    #pragma unroll
    for (int k = 0; k < 8; ++k) acc[k] = 0.f;
    switch (fc) {
        case 0:  psi_accum<0>(h, jc, tid, Kn, acc); break;
        case 1:  psi_accum<1>(h, jc, tid, Kn, acc); break;
        case 2:  psi_accum<2>(h, jc, tid, Kn, acc); break;
        case 3:  psi_accum<3>(h, jc, tid, Kn, acc); break;
        case 4:  psi_accum<4>(h, jc, tid, Kn, acc); break;
        case 5:  psi_accum<5>(h, jc, tid, Kn, acc); break;
        case 6:  psi_accum<6>(h, jc, tid, Kn, acc); break;
        case 7:  psi_accum<7>(h, jc, tid, Kn, acc); break;
        default: psi_accum<8>(h, jc, tid, Kn, acc); break;
    }
    #pragma unroll
    for (int off = 32; off; off >>= 1)
        #pragma unroll
        for (int k = 0; k < 8; ++k) acc[k] += __shfl_down(acc[k], off);
    __shared__ float red[4][8];
    const int lane = tid & 63, wv = tid >> 6;
    if (lane == 0) {
        #pragma unroll
        for (int k = 0; k < 8; ++k) red[wv][k] = acc[k];
    }
    __syncthreads();
    if (tid < 8) {
        int f = fc * 8 + tid;
        if (f < NF) {
            float s = (red[0][tid] + red[1][tid]) + (red[2][tid] + red[3][tid]);
            int A, B, C, D; f2abcd(f, A, B, C, D);
            Sp[(jc * 16 + h) * FP + f] = s * hdeg(A + B + C + D) *
                ((invfact(A) * invfact(B)) * (invfact(C) * invfact(D)));
        }
    }
}

// ---------------------------------------------------------------------------
// Kernel 3: fold Sp -> Sf (LDS); Z_j = sum_f q^a Sf; Vz = V/Z.
// Grid (16 j-tiles, 16 h), block 256.
// ---------------------------------------------------------------------------
__global__ __launch_bounds__(256) void zvz_kernel(
    const float* __restrict__ Qn, const float* __restrict__ Sp,
    const float* __restrict__ V4, float* __restrict__ Vz)
{
    __shared__ float Sf[FP];
    const int tid = threadIdx.x;
    const int h   = blockIdx.y;
    if (tid < FP) {
        float s = 0.f;
        #pragma unroll
        for (int jc = 0; jc < 4; ++jc) s += Sp[(jc * 16 + h) * FP + tid];
        Sf[tid] = s;
    }
    __syncthreads();
    const int j = blockIdx.x * 256 + tid;
    float4 q = ((const float4*)Qn)[h * SL + j];
    BUILD_POWERS(q)
    float z = 0.f;
    FOR_MONOMIALS({ z = fmaf((p0[a]*p1[b])*(p2[c]*p3[d]), Sf[f], z); })
    float inv = 1.f / z;
    float4 v = ((const float4*)V4)[h * SL + j];
    ((float4*)Vz)[h * SL + j] = make_float4(v.x*inv, v.y*inv, v.z*inv, v.w*inv);
}

// ---------------------------------------------------------------------------
// Kernel 4: Mp[jc][h][f][d] = c_f * sum over j-quarter of q^a Vz[d,j].
// Grid (9 fc, 16 h, 4 jc) = 576 blocks (2.25/CU).
// ---------------------------------------------------------------------------
template <int FC>
__device__ __forceinline__ void m_accum(int h, int jc, int tid,
        const float* __restrict__ Qn, const float* __restrict__ Vz,
        float acc[32])
{
    for (int u = 0; u < 4; ++u) {
        int j = jc * 1024 + u * 256 + tid;
        float4 q = ((const float4*)Qn)[h * SL + j];
        float4 v = ((const float4*)Vz)[h * SL + j];
        BUILD_POWERS(q)
        FOR_MONOMIALS({
            if (f >= FC * 8 && f < FC * 8 + 8) {
                const int fi = f - FC * 8;
                float m = (p0[a] * p1[b]) * (p2[c] * p3[d]);
                acc[fi*4+0] = fmaf(m, v.x, acc[fi*4+0]);
                acc[fi*4+1] = fmaf(m, v.y, acc[fi*4+1]);
                acc[fi*4+2] = fmaf(m, v.z, acc[fi*4+2]);
                acc[fi*4+3] = fmaf(m, v.w, acc[fi*4+3]);
            }
        })
    }
}

__global__ __launch_bounds__(256) void mmat_kernel(
    const float* __restrict__ Qn, const float* __restrict__ Vz,
    float* __restrict__ Mp)
{
    const int tid = threadIdx.x;
    const int fc  = blockIdx.x;
    const int h   = blockIdx.y;
    const int jc  = blockIdx.z;
    float acc[32];
    #pragma unroll
    for (int k = 0; k < 32; ++k) acc[k] = 0.f;
    switch (fc) {
        case 0:  m_accum<0>(h, jc, tid, Qn, Vz, acc); break;
        case 1:  m_accum<1>(h, jc, tid, Qn, Vz, acc); break;
        case 2:  m_accum<2>(h, jc, tid, Qn, Vz, acc); break;
        case 3:  m_accum<3>(h, jc, tid, Qn, Vz, acc); break;
        case 4:  m_accum<4>(h, jc, tid, Qn, Vz, acc); break;
        case 5:  m_accum<5>(h, jc, tid, Qn, Vz, acc); break;
        case 6:  m_accum<6>(h, jc, tid, Qn, Vz, acc); break;
        case 7:  m_accum<7>(h, jc, tid, Qn, Vz, acc); break;
        default: m_accum<8>(h, jc, tid, Qn, Vz, acc); break;
    }
    #pragma unroll
    for (int off = 32; off; off >>= 1)
        #pragma unroll
        for (int k = 0; k < 32; ++k) acc[k] += __shfl_down(acc[k], off);
    __shared__ float red[4][32];
    const int lane = tid & 63, wv = tid >> 6;
    if (lane == 0) {
        #pragma unroll
        for (int k = 0; k < 32; ++k) red[wv][k] = acc[k];
    }
    __syncthreads();
    if (tid < 32) {
        int fi = tid >> 2, dd = tid & 3;
        int f = fc * 8 + fi;
        if (f < NF) {
            float s = (red[0][tid] + red[1][tid]) + (red[2][tid] + red[3][tid]);
            int A, B, C, D; f2abcd(f, A, B, C, D);
            s *= hdeg(A + B + C + D) *
                 (invfact(A) * invfact(B)) * (invfact(C) * invfact(D));
            Mp[((jc * 16 + h) * FP + f) * 4 + dd] = s;
        }
    }
}

// ---------------------------------------------------------------------------
// Kernel 5: fused AO + output projection + bias + residual.
// Grid (128 tiles of 32 pos, 4 c-blocks of 64 ch) = 512 blocks (2/CU,
// 8 waves/CU). LDS: M fold 18 KB + AO 8.25 KB. Phase A: thread -> 2
// (pos,h) pairs, M via LDS broadcast. Phase B: 8 ch/thread, Wo float4.
// ---------------------------------------------------------------------------
__global__ __launch_bounds__(256) void outfuse_kernel(
    const float* __restrict__ Kn, const float* __restrict__ Mp,
    const float* __restrict__ Wo, const float* __restrict__ bo,
    const float* __restrict__ X, float* __restrict__ Y)
{
    __shared__ __align__(16) float ML[16 * FP * 4];    // 18 KB
    __shared__ float AOL[64 * 33];                     // 8.25 KB
    const int tid = threadIdx.x;
    const int it  = blockIdx.x;
    const int cb  = blockIdx.y;
    const int i0  = it * 32;

    {   // fold Mp (4 jc partials) -> ML  [f=70,71 slots: unused garbage]
        const float4* Mp4 = (const float4*)Mp;
        float4* ML4 = (float4*)ML;
        #pragma unroll
        for (int w = 0; w < 5; ++w) {
            int e = tid + w * 256;                     // [0, 16*FP=1152)
            if (e < 16 * FP) {
                float4 a = Mp4[e];
                float4 b = Mp4[16 * FP + e];
                float4 c = Mp4[32 * FP + e];
                float4 d = Mp4[48 * FP + e];
                ML4[e] = make_float4((a.x+b.x)+(c.x+d.x), (a.y+b.y)+(c.y+d.y),
                                     (a.z+b.z)+(c.z+d.z), (a.w+b.w)+(c.w+d.w));
            }
        }
    }
    __syncthreads();

    #pragma unroll
    for (int r = 0; r < 2; ++r) {                      // 512 (pos,h) pairs
        int p = tid + r * 256;
        int pos = p & 31, h = p >> 5;
        float4 k = ((const float4*)Kn)[h * SL + i0 + pos];
        BUILD_POWERS(k)
        const float4* Mh = ((const float4*)ML) + h * FP;
        float a0 = 0.f, a1 = 0.f, a2 = 0.f, a3 = 0.f;
        FOR_MONOMIALS({
            float m = (p0[a] * p1[b]) * (p2[c] * p3[d]);
            float4 mm = Mh[f];                         // LDS broadcast
            a0 = fmaf(m, mm.x, a0); a1 = fmaf(m, mm.y, a1);
            a2 = fmaf(m, mm.z, a2); a3 = fmaf(m, mm.w, a3);
        })
        AOL[(h * 4 + 0) * 33 + pos] = a0;
        AOL[(h * 4 + 1) * 33 + pos] = a1;
        AOL[(h * 4 + 2) * 33 + pos] = a2;
        AOL[(h * 4 + 3) * 33 + pos] = a3;
    }
    __syncthreads();

    const int pos = tid & 31, cg = tid >> 5;           // 8 groups of 8 ch
    const int chb = cb * 64 + cg * 8;
    float acc[8];
    #pragma unroll
    for (int u = 0; u < 8; ++u) acc[u] = 0.f;
    #pragma unroll 4
    for (int ob = 0; ob < 16; ++ob) {                  // 4 o's per ob
        float x0 = AOL[(ob * 4 + 0) * 33 + pos];
        float x1 = AOL[(ob * 4 + 1) * 33 + pos];
        float x2 = AOL[(ob * 4 + 2) * 33 + pos];
        float x3 = AOL[(ob * 4 + 3) * 33 + pos];
        #pragma unroll
        for (int u = 0; u < 8; ++u) {
            float4 w4 = ((const float4*)Wo)[(chb + u) * 16 + ob];
            acc[u] = fmaf(w4.x, x0, fmaf(w4.y, x1,
                     fmaf(w4.z, x2, fmaf(w4.w, x3, acc[u]))));
        }
    }
    #pragma unroll
    for (int u = 0; u < 8; ++u) {
        int ch = chb + u;
        Y[ch * SL + i0 + pos] = acc[u] + bo[ch] + X[ch * SL + i0 + pos];
    }
}

// ---------------------------------------------------------------------------
extern "C" void kernel_launch(void* const* d_in, const int* in_sizes, int n_in,
                              void* d_out, int out_size, void* d_ws, size_t ws_size,
                              hipStream_t stream)
{
    const float* X  = (const float*)d_in[0];
    const float* Wq = (const float*)d_in[1];
    const float* bq = (const float*)d_in[2];
    const float* Wk = (const float*)d_in[3];
    const float* bk = (const float*)d_in[4];
    const float* Wv = (const float*)d_in[5];
    const float* bv = (const float*)d_in[6];
    const float* Wo = (const float*)d_in[7];
    const float* bo = (const float*)d_in[8];
    float* Y = (float*)d_out;

    char* w = (char*)d_ws;
    float* Qn = (float*)(w + (0 << 20));   // [16][SL][4]        1 MB
    float* Kn = (float*)(w + (1 << 20));   // [16][SL][4]        1 MB
    float* V4 = (float*)(w + (2 << 20));   // [16][SL][4]        1 MB
    float* Vz = (float*)(w + (3 << 20));   // [16][SL][4]        1 MB
    float* Sp = (float*)(w + (4 << 20));   // [4][16][FP]        18 KB
    float* Mp = (float*)(w + (4 << 20) + (128 << 10)); // [4][16][FP][4] 72 KB

    qkv_kernel<<<dim3(64, 12), 256, 0, stream>>>(X, Wq, bq, Wk, bk, Wv, bv,
                                                 Qn, Kn, V4);
    ssum_kernel<<<dim3(9, 16, 4), 256, 0, stream>>>(Kn, Sp);
    zvz_kernel<<<dim3(16, 16), 256, 0, stream>>>(Qn, Sp, V4, Vz);
    mmat_kernel<<<dim3(9, 16, 4), 256, 0, stream>>>(Qn, Vz, Mp);
    outfuse_kernel<<<dim3(128, 4), 256, 0, stream>>>(Kn, Mp, Wo, bo, X, Y);
}